// Round 17
// baseline (157.763 us; speedup 1.0000x reference)
//
#include <hip/hip_runtime.h>
#include <hip/hip_bf16.h>

typedef unsigned short u16;
typedef __attribute__((ext_vector_type(8))) short short8;
typedef __attribute__((ext_vector_type(2))) float f32x2;
typedef __attribute__((ext_vector_type(4))) float f32x4;
typedef __attribute__((ext_vector_type(16))) float f32x16;

#define NH 16
#define HD 64
#define SEQ 2048
#define NBATCH 2
#define DM 1024

#define GLOAD_LDS(g, l)                                                              \
  __builtin_amdgcn_global_load_lds((__attribute__((address_space(1))) const void*)(g), \
                                   (__attribute__((address_space(3))) void*)(l), 16, 0, 0)

__device__ __forceinline__ u16 f2bf(float f) {
  __hip_bfloat16 h = __float2bfloat16(f);
  return *reinterpret_cast<u16*>(&h);
}
__device__ __forceinline__ float bf2f(u16 u) {
  union { unsigned int i; float f; } v; v.i = ((unsigned int)u) << 16; return v.f;
}
__device__ __forceinline__ f32x4 mfma16(short8 a, short8 b, f32x4 c) {
  return __builtin_amdgcn_mfma_f32_16x16x32_bf16(a, b, c, 0, 0, 0);
}
__device__ __forceinline__ f32x16 mfma32(short8 a, short8 b, f32x16 c) {
  return __builtin_amdgcn_mfma_f32_32x32x16_bf16(a, b, c, 0, 0, 0);
}

// ---------------- fused prep: convert | transpose(w_in) | transpose(w_out) | sincos ----
// R15: 4 independent memory-bound kernels -> 1 dispatch (sectioned by blockIdx).
__global__ __launch_bounds__(256) void k_prep(const float* __restrict__ inputs,
                                              u16* __restrict__ Xbf,
                                              const float* __restrict__ w_in,
                                              u16* __restrict__ WinT,
                                              const float* __restrict__ w_out,
                                              u16* __restrict__ WoutT,
                                              float2* __restrict__ SC) {
  __shared__ float t[32][33];
  int blk = blockIdx.x, tid = threadIdx.x;
  if (blk < 4096) {
    // f32 -> bf16 convert (4M floats as 1M float4)
    int i = blk * 256 + tid;
    float4 v = reinterpret_cast<const float4*>(inputs)[i];
    union { u16 h[4]; unsigned long long u; } o;
    o.h[0] = f2bf(v.x); o.h[1] = f2bf(v.y); o.h[2] = f2bf(v.z); o.h[3] = f2bf(v.w);
    reinterpret_cast<unsigned long long*>(Xbf)[i] = o.u;
  } else if (blk < 4096 + 3072 + 1024) {
    // f32 [R][C] -> bf16 [C][R] transpose (w_in: 1024x3072; w_out: 1024x1024)
    const float* src; u16* dst; int C, bx, by;
    if (blk < 4096 + 3072) {
      int b2 = blk - 4096; src = w_in; dst = WinT; C = 3072; bx = b2 % 96; by = b2 / 96;
    } else {
      int b2 = blk - (4096 + 3072); src = w_out; dst = WoutT; C = 1024; bx = b2 & 31; by = b2 >> 5;
    }
    const int R = 1024;
    int c0 = bx * 32, r0 = by * 32;
    int tx = tid & 31, ty = tid >> 5;
#pragma unroll
    for (int i = 0; i < 4; ++i)
      t[ty + 8 * i][tx] = src[(size_t)(r0 + ty + 8 * i) * C + c0 + tx];
    __syncthreads();
#pragma unroll
    for (int i = 0; i < 4; ++i)
      dst[(size_t)(c0 + ty + 8 * i) * R + r0 + tx] = f2bf(t[tx][ty + 8 * i]);
  } else {
    // RoPE sin/cos table: [pos][i] -> (sin, cos), 2048*32 entries
    int idx = (blk - 8192) * 256 + tid;
    int p = idx >> 5, i = idx & 31;
    const float l2ts = 0.41524101186092029f;  // log2(10000)/32
    float inv = exp2f(-(float)i * l2ts);      // 10000^(-i/32)
    float arg = (float)p * inv;
    float s, c;
    sincosf(arg, &s, &c);
    SC[idx] = make_float2(s, c);
  }
}

// ---------------- RoPE in-place on Q (scaled 1/8) and K ----------------
// Separate streaming kernel (coalesced uint4 loads): ~7us. Fusing this into
// the GEMM epilogue costs ~45us of uncoalesced segpos/sc gathers — R6 post-mortem.
__global__ void k_rope(u16* __restrict__ Q, u16* __restrict__ K,
                       const int* __restrict__ segpos, const float2* __restrict__ sc) {
  int rid = blockIdx.x * 256 + threadIdx.x;  // 2 * B*H*S rows
  u16* buf = (rid < NBATCH * NH * SEQ) ? Q : K;
  float qs = (rid < NBATCH * NH * SEQ) ? 0.125f : 1.0f;
  int r = rid & (NBATCH * NH * SEQ - 1);
  int b = r >> 15;  // / (NH*SEQ)
  int s = r & (SEQ - 1);
  int pos = segpos[b * SEQ + s];
  const float2* scp = sc + (size_t)pos * 32;
  u16* row = buf + (size_t)r * HD;
  uint4 v[8];
#pragma unroll
  for (int i = 0; i < 8; ++i) v[i] = reinterpret_cast<uint4*>(row)[i];
  u16* e = reinterpret_cast<u16*>(v);
#pragma unroll
  for (int i = 0; i < 32; ++i) {
    float a = bf2f(e[i]), bq = bf2f(e[i + 32]);
    float2 t = scp[i];
    float na = (a * t.y - bq * t.x) * qs;
    float nb = (bq * t.y + a * t.x) * qs;
    e[i] = f2bf(na); e[i + 32] = f2bf(nb);
  }
#pragma unroll
  for (int i = 0; i < 8; ++i) reinterpret_cast<uint4*>(row)[i] = v[i];
}

// ---------------- bf16 MFMA GEMM, 128x128 tile, BK=64, global_load_lds ----------------
// A [M][1024] row-major bf16; Bt [N][1024] row-major bf16 (= B^T).
// T2 XOR-swizzle, both-sides-or-neither form (R14: conflicts 9.4M -> ~0,
// gemm<0> 68 -> <62us): LDS linear; global source column and LDS read column
// both XOR'd by the same involution (elem-slot ^= row&7).
// MODE 0: epilogue scatters in_proj into Q/K [b][h][s][64] and TILED
//         Vt [b][h][kt=s/32][d=64][kv=s%32] (R13).
// MODE 1: plain f32 store to out [M][N].
// XCD-aware block swizzle (T1): grid sizes 768/256 are %8==0 -> bijective.
template <int MODE>
__global__ __launch_bounds__(256) void k_gemm(const u16* __restrict__ A, const u16* __restrict__ Bt,
                                              int N, u16* __restrict__ q, u16* __restrict__ kk,
                                              u16* __restrict__ vt, float* __restrict__ out) {
  __shared__ alignas(16) u16 As[128][64];
  __shared__ alignas(16) u16 Bs[128][64];
  const int K = 1024;
  int tid = threadIdx.x;
  int lane = tid & 63, w = tid >> 6;
  int wr = w >> 1, wc = w & 1;
  int col = lane & 15, grp = lane >> 4;
  int cx = col & 7;  // = row&7 of every fragment row this lane reads
  int bid = blockIdx.y * gridDim.x + blockIdx.x;
  int qq = (gridDim.x * gridDim.y) >> 3;
  int swz = (bid & 7) * qq + (bid >> 3);
  int m0 = (swz / gridDim.x) * 128;
  int n0 = (swz % gridDim.x) * 128;
  // global_load_lds chunk geometry: chunk = 1KB = 8 rows of 64 bf16; lane
  // writes LDS bytes [chunk*1024 + lane*16) -> row chunk*8+(lane>>3).
  // T2 pre-swizzle: source column slot XOR'd with row&7 (= lane>>3).
  int crow = lane >> 3;
  int ccol = ((lane & 7) ^ (lane >> 3)) * 8;
  f32x4 zero4 = {0.f, 0.f, 0.f, 0.f};
  f32x4 acc[4][4];
#pragma unroll
  for (int i = 0; i < 4; ++i)
#pragma unroll
    for (int j = 0; j < 4; ++j) acc[i][j] = zero4;

  for (int k0 = 0; k0 < K; k0 += 64) {
    __syncthreads();  // previous compute done before overwrite
#pragma unroll
    for (int c = 0; c < 4; ++c) {
      int chunk = w * 4 + c;
      int r = chunk * 8 + crow;
      GLOAD_LDS(&A[(size_t)(m0 + r) * K + k0 + ccol], &As[0][0] + chunk * 512);
      GLOAD_LDS(&Bt[(size_t)(n0 + r) * K + k0 + ccol], &Bs[0][0] + chunk * 512);
    }
    __syncthreads();  // vmcnt drained by barrier -> tiles visible
#pragma unroll
    for (int kf = 0; kf < 2; ++kf) {
      short8 af[4], bfr[4];
      int sw = ((kf * 4 + grp) ^ cx) * 8;  // swizzled read column (elems)
#pragma unroll
      for (int i = 0; i < 4; ++i)
        af[i] = *reinterpret_cast<const short8*>(&As[wr * 64 + i * 16 + col][sw]);
#pragma unroll
      for (int i = 0; i < 4; ++i)
        bfr[i] = *reinterpret_cast<const short8*>(&Bs[wc * 64 + i * 16 + col][sw]);
#pragma unroll
      for (int mi = 0; mi < 4; ++mi)
#pragma unroll
        for (int ni = 0; ni < 4; ++ni) acc[mi][ni] = mfma16(af[mi], bfr[ni], acc[mi][ni]);
    }
  }
#pragma unroll
  for (int mi = 0; mi < 4; ++mi)
#pragma unroll
    for (int ni = 0; ni < 4; ++ni)
#pragma unroll
      for (int j = 0; j < 4; ++j) {
        int m = m0 + wr * 64 + mi * 16 + grp * 4 + j;
        int n = n0 + wc * 64 + ni * 16 + col;
        float v = acc[mi][ni][j];
        if (MODE == 0) {
          int b = m >> 11, s = m & 2047;
          int h = n / 192, f = n - h * 192;
          u16 bv = f2bf(v);
          if (f < 64)
            q[(((size_t)(b * NH + h) * SEQ + s) << 6) + f] = bv;
          else if (f < 128)
            kk[(((size_t)(b * NH + h) * SEQ + s) << 6) + (f - 64)] = bv;
          else
            vt[(size_t)(b * NH + h) * (HD * SEQ) + (size_t)(s >> 5) * 2048 +
               (f - 128) * 32 + (s & 31)] = bv;
        } else {
          out[(size_t)m * N + n] = v;
        }
      }
}

// ---------------- flash attention, causal, softcap 50 ----------------
// R9 structure: 4-wave blocks, grid 1024, uniform-work pairing (63-i, i),
// split-KV x4. Packed-f32 softmax (R11). TILED Vt (R13). Raw exp2 + diag
// peel (R16: VALUBusy 42->21%). R17:
// (a) IN-PLACE K-prefetch: after QK consumes kf, those 16 regs are dead ->
//     reload kf with the NEXT tile's K right there (clamped to qc; the last
//     prefetch lands on the diag tile's K, consumed by the owning wave).
//     K-load latency now spans softmax+pack+PV (~600cy) instead of stalling
//     QK. Unlike R8/R12 there is NO second buffer: peak pressure +16 regs
//     (96 -> ~112 < 128 cap). Spill tripwire: WRITE_SIZE 8.2MB.
// (b) parallel combine: waves 1-3 write cbuf[w-1] concurrently, ONE barrier,
//     w0 sums — replaces 3 serial barrier rounds.
// 4 waves/SIMD is the occupancy ceiling for this state size (R10).
#define TILE_BODY(KBASE, DIAG, DO_PRE, PRE_KT)                                          \
  {                                                                                     \
    int kbase = (KBASE);                                                                \
    f32x16 sacc;                                                                        \
    _Pragma("unroll") for (int r = 0; r < 16; ++r) sacc[r] = 0.f;                       \
    __builtin_amdgcn_s_setprio(1);                                                      \
    _Pragma("unroll") for (int d0 = 0; d0 < 4; ++d0) sacc = mfma32(kf[d0], qf[d0], sacc); \
    __builtin_amdgcn_s_setprio(0);                                                      \
    if (DO_PRE) {                                                                       \
      _Pragma("unroll") for (int d0 = 0; d0 < 4; ++d0)                                  \
        kf[d0] = *reinterpret_cast<const short8*>(                                      \
            &Kb[(size_t)((PRE_KT) * 32 + ql) * HD + d0 * 16 + hi * 8]);                 \
    }                                                                                   \
    const u16* Vtile = Vb + (size_t)(kbase >> 5) * 2048;                                \
    short8 vf[2][2];                                                                    \
    _Pragma("unroll") for (int c = 0; c < 2; ++c)                                       \
      _Pragma("unroll") for (int dh = 0; dh < 2; ++dh)                                  \
        vf[c][dh] = *reinterpret_cast<const short8*>(                                   \
            &Vtile[(dh * 32 + ql) * 32 + c * 16 + hi * 8]);                             \
    float p[16];                                                                        \
    _Pragma("unroll") for (int r2 = 0; r2 < 8; ++r2) {                                  \
      f32x2 s2 = {sacc[2 * r2], sacc[2 * r2 + 1]};                                      \
      f32x2 t2 = s2 * s2;                                                               \
      f32x2 u2 = __builtin_elementwise_fma(t2, C52, C32);                               \
      u2 = __builtin_elementwise_fma(t2, u2, L2E2);                                     \
      f32x2 v2 = s2 * u2;                                                               \
      float p0 = __builtin_amdgcn_exp2f(v2.x);                                          \
      float p1 = __builtin_amdgcn_exp2f(v2.y);                                          \
      if (DIAG) {                                                                       \
        int r = 2 * r2;                                                                 \
        int kpos0 = kbase + (r & 3) + 8 * (r >> 2) + 4 * hi;                            \
        int kpos1 = kbase + ((r + 1) & 3) + 8 * ((r + 1) >> 2) + 4 * hi;                \
        if (kpos0 > qbase + ql) p0 = 0.f;                                               \
        if (kpos1 > qbase + ql) p1 = 0.f;                                               \
      }                                                                                 \
      p[2 * r2] = p0;                                                                   \
      p[2 * r2 + 1] = p1;                                                               \
      lsum2 += (f32x2){p0, p1};                                                         \
    }                                                                                   \
    short8 pfrag[2];                                                                    \
    _Pragma("unroll") for (int c = 0; c < 2; ++c) {                                     \
      unsigned int a0, a1, b0, b1;                                                      \
      asm("v_cvt_pk_bf16_f32 %0, %1, %2" : "=v"(a0) : "v"(p[8 * c + 0]), "v"(p[8 * c + 1])); \
      asm("v_cvt_pk_bf16_f32 %0, %1, %2" : "=v"(a1) : "v"(p[8 * c + 2]), "v"(p[8 * c + 3])); \
      asm("v_cvt_pk_bf16_f32 %0, %1, %2" : "=v"(b0) : "v"(p[8 * c + 4]), "v"(p[8 * c + 5])); \
      asm("v_cvt_pk_bf16_f32 %0, %1, %2" : "=v"(b1) : "v"(p[8 * c + 6]), "v"(p[8 * c + 7])); \
      asm("v_permlane32_swap_b32 %0, %1" : "+v"(a0), "+v"(b0));                         \
      asm("v_permlane32_swap_b32 %0, %1" : "+v"(a1), "+v"(b1));                         \
      union { unsigned int u[4]; short8 s8; } pk;                                       \
      pk.u[0] = a0; pk.u[1] = a1; pk.u[2] = b0; pk.u[3] = b1;                           \
      pfrag[c] = pk.s8;                                                                 \
    }                                                                                   \
    __builtin_amdgcn_s_setprio(1);                                                      \
    _Pragma("unroll") for (int c = 0; c < 2; ++c) {                                     \
      xacc0 = mfma32(pfrag[c], vf[c][0], xacc0);                                        \
      xacc1 = mfma32(pfrag[c], vf[c][1], xacc1);                                        \
    }                                                                                   \
    __builtin_amdgcn_s_setprio(0);                                                      \
  }

__global__ __launch_bounds__(256, 4) void k_attn(const u16* __restrict__ Q,
                                                 const u16* __restrict__ K,
                                                 const u16* __restrict__ Vt,
                                                 u16* __restrict__ X) {
  int lin = blockIdx.x;          // 0..1023
  int xcd = lin & 7;             // dispatch round-robins XCDs
  int jj = lin >> 3;             // 0..127
  int bh = xcd * 4 + (jj & 3);   // 4 heads per XCD -> K+V 2MB/XCD, L2-resident
  int iq = jj >> 2;              // 0..31
  int tid = threadIdx.x, lane = tid & 63, w = tid >> 6;
  int ql = lane & 31, hi = lane >> 5;
  const u16* Qb = Q + (size_t)bh * SEQ * HD;
  const u16* Kb = K + (size_t)bh * SEQ * HD;
  const u16* Vb = Vt + (size_t)bh * HD * SEQ;
  int b = bh >> 4, h = bh & 15;
  size_t ob = (size_t)b * SEQ * DM + (size_t)h * HD;

  __shared__ float cbuf[3][64][34];  // parallel combine: one slice per wave 1..3

  const float L2E = 1.4426950408889634f;
  const f32x2 C32 = {-1.9235933878519513e-4f, -1.9235933878519513e-4f};  // -L2E/7500
  const f32x2 C52 = {3.0777494205630686e-8f, 3.0777494205630686e-8f};    // 2*L2E/(15*50^4)
  const f32x2 L2E2 = {L2E, L2E};

  for (int half = 0; half < 2; ++half) {
    int qc = half ? iq : 63 - iq;  // pair sums to 65 tiles -> uniform blocks
    int qbase = qc * 32;

    // Q fragments (B-operand): Q[qbase+ql][d0*16 + hi*8 .. +8]
    short8 qf[4];
#pragma unroll
    for (int d0 = 0; d0 < 4; ++d0)
      qf[d0] = *reinterpret_cast<const short8*>(&Qb[(size_t)(qbase + ql) * HD + d0 * 16 + hi * 8]);

    f32x16 xacc0, xacc1;
#pragma unroll
    for (int r = 0; r < 16; ++r) { xacc0[r] = 0.f; xacc1[r] = 0.f; }
    f32x2 lsum2 = {0.f, 0.f};

    // prime kf (clamped: waves with no main tiles prime the diag tile's K)
    short8 kf[4];
    {
      int kt0 = (w < qc) ? w : qc;
#pragma unroll
      for (int d0 = 0; d0 < 4; ++d0)
        kf[d0] = *reinterpret_cast<const short8*>(
            &Kb[(size_t)(kt0 * 32 + ql) * HD + d0 * 16 + hi * 8]);
    }

    // main tiles (kt < qc): mask compiled out; in-place prefetch of next K
    // (clamped to qc -> last prefetch loads the diag tile's K).
    for (int kt = w; kt < qc; kt += 4) {
      int ktn = kt + 4;
      if (ktn > qc) ktn = qc;
      TILE_BODY(kt * 32, false, true, ktn)
    }
    // diag tile (kt == qc): owned by wave (qc & 3); kf already primed.
    if ((qc & 3) == w) TILE_BODY(qc * 32, true, false, 0)

    float lsum = lsum2.x + lsum2.y;

    // ---- parallel combine of 4 waves' partials (plain sums; M=0 softmax) ----
    if (w > 0) {
#pragma unroll
      for (int r = 0; r < 16; ++r) {
        cbuf[w - 1][lane][r] = xacc0[r];
        cbuf[w - 1][lane][16 + r] = xacc1[r];
      }
      cbuf[w - 1][lane][32] = lsum;
    }
    __syncthreads();

    if (w == 0) {
#pragma unroll
      for (int s = 0; s < 3; ++s) {
#pragma unroll
        for (int r = 0; r < 16; ++r) {
          xacc0[r] += cbuf[s][lane][r];
          xacc1[r] += cbuf[s][lane][16 + r];
        }
        lsum += cbuf[s][lane][32];
      }
      // lanes q and q+32 hold the two k-half partials of row q
      lsum += __shfl_xor(lsum, 32, 64);
      float rinv = __builtin_amdgcn_rcpf(lsum);  // valid for q = ql on every lane

#pragma unroll
      for (int r = 0; r < 16; ++r) {
        int qrel = (r & 3) + 8 * (r >> 2) + 4 * hi;
        float rv = __shfl(rinv, qrel, 64);
        size_t row = ob + (size_t)(qbase + qrel) * DM;
        X[row + ql] = f2bf(xacc0[r] * rv);
        X[row + 32 + ql] = f2bf(xacc1[r] * rv);
      }
    }
    __syncthreads();  // cbuf safe for reuse by next half
  }
}

extern "C" void kernel_launch(void* const* d_in, const int* in_sizes, int n_in,
                              void* d_out, int out_size, void* d_ws, size_t ws_size,
                              hipStream_t stream) {
  const float* inputs = (const float*)d_in[0];
  const int* segpos = (const int*)d_in[1];
  // d_in[2] = mask: causal tril, known analytically — unused.
  const float* w_in = (const float*)d_in[3];
  const float* w_out = (const float*)d_in[4];
  float* out = (float*)d_out;
  char* ws = (char*)d_ws;

  size_t o = 0;
  u16* Xbf = (u16*)(ws + o); o += (size_t)4096 * 1024 * 2;   // inputs bf16; reused as attn output
  u16* WinT = (u16*)(ws + o); o += (size_t)3072 * 1024 * 2;  // w_in^T bf16
  u16* WoutT = (u16*)(ws + o); o += (size_t)1024 * 1024 * 2; // w_out^T bf16
  u16* Qb = (u16*)(ws + o); o += (size_t)NBATCH * NH * SEQ * HD * 2;
  u16* Kb = (u16*)(ws + o); o += (size_t)NBATCH * NH * SEQ * HD * 2;
  u16* Vt = (u16*)(ws + o); o += (size_t)NBATCH * NH * HD * SEQ * 2;
  float2* SC = (float2*)(ws + o); o += (size_t)SEQ * 32 * sizeof(float2);

  k_prep<<<8448, 256, 0, stream>>>(inputs, Xbf, w_in, WinT, w_out, WoutT, SC);
  k_gemm<0><<<dim3(24, 32), 256, 0, stream>>>(Xbf, WinT, 3072, Qb, Kb, Vt, nullptr);
  k_rope<<<512, 256, 0, stream>>>(Qb, Kb, segpos, SC);
  k_attn<<<1024, 256, 0, stream>>>(Qb, Kb, Vt, Xbf);
  k_gemm<1><<<dim3(8, 32), 256, 0, stream>>>(Xbf, WoutT, 1024, nullptr, nullptr, nullptr, out);
}

// Round 18
// 155.255 us; speedup vs baseline: 1.0162x; 1.0162x over previous
//
#include <hip/hip_runtime.h>
#include <hip/hip_bf16.h>

typedef unsigned short u16;
typedef __attribute__((ext_vector_type(8))) short short8;
typedef __attribute__((ext_vector_type(2))) float f32x2;
typedef __attribute__((ext_vector_type(4))) float f32x4;
typedef __attribute__((ext_vector_type(16))) float f32x16;

#define NH 16
#define HD 64
#define SEQ 2048
#define NBATCH 2
#define DM 1024

#define GLOAD_LDS(g, l)                                                              \
  __builtin_amdgcn_global_load_lds((__attribute__((address_space(1))) const void*)(g), \
                                   (__attribute__((address_space(3))) void*)(l), 16, 0, 0)

__device__ __forceinline__ u16 f2bf(float f) {
  __hip_bfloat16 h = __float2bfloat16(f);
  return *reinterpret_cast<u16*>(&h);
}
__device__ __forceinline__ float bf2f(u16 u) {
  union { unsigned int i; float f; } v; v.i = ((unsigned int)u) << 16; return v.f;
}
__device__ __forceinline__ f32x4 mfma16(short8 a, short8 b, f32x4 c) {
  return __builtin_amdgcn_mfma_f32_16x16x32_bf16(a, b, c, 0, 0, 0);
}
__device__ __forceinline__ f32x16 mfma32(short8 a, short8 b, f32x16 c) {
  return __builtin_amdgcn_mfma_f32_32x32x16_bf16(a, b, c, 0, 0, 0);
}

// ---------------- fused prep: convert | transpose(w_in) | transpose(w_out) | sincos ----
// R15: 4 independent memory-bound kernels -> 1 dispatch (sectioned by blockIdx).
__global__ __launch_bounds__(256) void k_prep(const float* __restrict__ inputs,
                                              u16* __restrict__ Xbf,
                                              const float* __restrict__ w_in,
                                              u16* __restrict__ WinT,
                                              const float* __restrict__ w_out,
                                              u16* __restrict__ WoutT,
                                              float2* __restrict__ SC) {
  __shared__ float t[32][33];
  int blk = blockIdx.x, tid = threadIdx.x;
  if (blk < 4096) {
    // f32 -> bf16 convert (4M floats as 1M float4)
    int i = blk * 256 + tid;
    float4 v = reinterpret_cast<const float4*>(inputs)[i];
    union { u16 h[4]; unsigned long long u; } o;
    o.h[0] = f2bf(v.x); o.h[1] = f2bf(v.y); o.h[2] = f2bf(v.z); o.h[3] = f2bf(v.w);
    reinterpret_cast<unsigned long long*>(Xbf)[i] = o.u;
  } else if (blk < 4096 + 3072 + 1024) {
    // f32 [R][C] -> bf16 [C][R] transpose (w_in: 1024x3072; w_out: 1024x1024)
    const float* src; u16* dst; int C, bx, by;
    if (blk < 4096 + 3072) {
      int b2 = blk - 4096; src = w_in; dst = WinT; C = 3072; bx = b2 % 96; by = b2 / 96;
    } else {
      int b2 = blk - (4096 + 3072); src = w_out; dst = WoutT; C = 1024; bx = b2 & 31; by = b2 >> 5;
    }
    const int R = 1024;
    int c0 = bx * 32, r0 = by * 32;
    int tx = tid & 31, ty = tid >> 5;
#pragma unroll
    for (int i = 0; i < 4; ++i)
      t[ty + 8 * i][tx] = src[(size_t)(r0 + ty + 8 * i) * C + c0 + tx];
    __syncthreads();
#pragma unroll
    for (int i = 0; i < 4; ++i)
      dst[(size_t)(c0 + ty + 8 * i) * R + r0 + tx] = f2bf(t[tx][ty + 8 * i]);
  } else {
    // RoPE sin/cos table: [pos][i] -> (sin, cos), 2048*32 entries
    int idx = (blk - 8192) * 256 + tid;
    int p = idx >> 5, i = idx & 31;
    const float l2ts = 0.41524101186092029f;  // log2(10000)/32
    float inv = exp2f(-(float)i * l2ts);      // 10000^(-i/32)
    float arg = (float)p * inv;
    float s, c;
    sincosf(arg, &s, &c);
    SC[idx] = make_float2(s, c);
  }
}

// ---------------- RoPE in-place on Q (scaled 1/8) and K ----------------
// Separate streaming kernel (coalesced uint4 loads): ~7us. Fusing this into
// the GEMM epilogue costs ~45us of uncoalesced segpos/sc gathers — R6 post-mortem.
__global__ void k_rope(u16* __restrict__ Q, u16* __restrict__ K,
                       const int* __restrict__ segpos, const float2* __restrict__ sc) {
  int rid = blockIdx.x * 256 + threadIdx.x;  // 2 * B*H*S rows
  u16* buf = (rid < NBATCH * NH * SEQ) ? Q : K;
  float qs = (rid < NBATCH * NH * SEQ) ? 0.125f : 1.0f;
  int r = rid & (NBATCH * NH * SEQ - 1);
  int b = r >> 15;  // / (NH*SEQ)
  int s = r & (SEQ - 1);
  int pos = segpos[b * SEQ + s];
  const float2* scp = sc + (size_t)pos * 32;
  u16* row = buf + (size_t)r * HD;
  uint4 v[8];
#pragma unroll
  for (int i = 0; i < 8; ++i) v[i] = reinterpret_cast<uint4*>(row)[i];
  u16* e = reinterpret_cast<u16*>(v);
#pragma unroll
  for (int i = 0; i < 32; ++i) {
    float a = bf2f(e[i]), bq = bf2f(e[i + 32]);
    float2 t = scp[i];
    float na = (a * t.y - bq * t.x) * qs;
    float nb = (bq * t.y + a * t.x) * qs;
    e[i] = f2bf(na); e[i + 32] = f2bf(nb);
  }
#pragma unroll
  for (int i = 0; i < 8; ++i) reinterpret_cast<uint4*>(row)[i] = v[i];
}

// ---------------- bf16 MFMA GEMM, 128x128 tile, BK=64, global_load_lds ----------------
// A [M][1024] row-major bf16; Bt [N][1024] row-major bf16 (= B^T).
// T2 XOR-swizzle, both-sides-or-neither form (R14: conflicts 9.4M -> ~0,
// gemm<0> 68 -> <62us): LDS linear; global source column and LDS read column
// both XOR'd by the same involution (elem-slot ^= row&7).
// MODE 0: epilogue scatters in_proj into Q/K [b][h][s][64] and TILED
//         Vt [b][h][kt=s/32][d=64][kv=s%32] (R13).
// MODE 1: plain f32 store to out [M][N].
// XCD-aware block swizzle (T1): grid sizes 768/256 are %8==0 -> bijective.
template <int MODE>
__global__ __launch_bounds__(256) void k_gemm(const u16* __restrict__ A, const u16* __restrict__ Bt,
                                              int N, u16* __restrict__ q, u16* __restrict__ kk,
                                              u16* __restrict__ vt, float* __restrict__ out) {
  __shared__ alignas(16) u16 As[128][64];
  __shared__ alignas(16) u16 Bs[128][64];
  const int K = 1024;
  int tid = threadIdx.x;
  int lane = tid & 63, w = tid >> 6;
  int wr = w >> 1, wc = w & 1;
  int col = lane & 15, grp = lane >> 4;
  int cx = col & 7;  // = row&7 of every fragment row this lane reads
  int bid = blockIdx.y * gridDim.x + blockIdx.x;
  int qq = (gridDim.x * gridDim.y) >> 3;
  int swz = (bid & 7) * qq + (bid >> 3);
  int m0 = (swz / gridDim.x) * 128;
  int n0 = (swz % gridDim.x) * 128;
  // global_load_lds chunk geometry: chunk = 1KB = 8 rows of 64 bf16; lane
  // writes LDS bytes [chunk*1024 + lane*16) -> row chunk*8+(lane>>3).
  // T2 pre-swizzle: source column slot XOR'd with row&7 (= lane>>3).
  int crow = lane >> 3;
  int ccol = ((lane & 7) ^ (lane >> 3)) * 8;
  f32x4 zero4 = {0.f, 0.f, 0.f, 0.f};
  f32x4 acc[4][4];
#pragma unroll
  for (int i = 0; i < 4; ++i)
#pragma unroll
    for (int j = 0; j < 4; ++j) acc[i][j] = zero4;

  for (int k0 = 0; k0 < K; k0 += 64) {
    __syncthreads();  // previous compute done before overwrite
#pragma unroll
    for (int c = 0; c < 4; ++c) {
      int chunk = w * 4 + c;
      int r = chunk * 8 + crow;
      GLOAD_LDS(&A[(size_t)(m0 + r) * K + k0 + ccol], &As[0][0] + chunk * 512);
      GLOAD_LDS(&Bt[(size_t)(n0 + r) * K + k0 + ccol], &Bs[0][0] + chunk * 512);
    }
    __syncthreads();  // vmcnt drained by barrier -> tiles visible
#pragma unroll
    for (int kf = 0; kf < 2; ++kf) {
      short8 af[4], bfr[4];
      int sw = ((kf * 4 + grp) ^ cx) * 8;  // swizzled read column (elems)
#pragma unroll
      for (int i = 0; i < 4; ++i)
        af[i] = *reinterpret_cast<const short8*>(&As[wr * 64 + i * 16 + col][sw]);
#pragma unroll
      for (int i = 0; i < 4; ++i)
        bfr[i] = *reinterpret_cast<const short8*>(&Bs[wc * 64 + i * 16 + col][sw]);
#pragma unroll
      for (int mi = 0; mi < 4; ++mi)
#pragma unroll
        for (int ni = 0; ni < 4; ++ni) acc[mi][ni] = mfma16(af[mi], bfr[ni], acc[mi][ni]);
    }
  }
#pragma unroll
  for (int mi = 0; mi < 4; ++mi)
#pragma unroll
    for (int ni = 0; ni < 4; ++ni)
#pragma unroll
      for (int j = 0; j < 4; ++j) {
        int m = m0 + wr * 64 + mi * 16 + grp * 4 + j;
        int n = n0 + wc * 64 + ni * 16 + col;
        float v = acc[mi][ni][j];
        if (MODE == 0) {
          int b = m >> 11, s = m & 2047;
          int h = n / 192, f = n - h * 192;
          u16 bv = f2bf(v);
          if (f < 64)
            q[(((size_t)(b * NH + h) * SEQ + s) << 6) + f] = bv;
          else if (f < 128)
            kk[(((size_t)(b * NH + h) * SEQ + s) << 6) + (f - 64)] = bv;
          else
            vt[(size_t)(b * NH + h) * (HD * SEQ) + (size_t)(s >> 5) * 2048 +
               (f - 128) * 32 + (s & 31)] = bv;
        } else {
          out[(size_t)m * N + n] = v;
        }
      }
}

// ---------------- flash attention, causal, softcap 50 ----------------
// R9 structure: 4-wave blocks, grid 1024, uniform-work pairing (63-i, i),
// split-KV x4. Packed-f32 softmax (R11). TILED Vt (R13). Raw exp2 + diag
// peel (R16: VALUBusy 42->21%). R18: K-prefetch REVERTED (R17 spilled —
// arch 64 + AGPR 64 = 128 = the (256,4) cap; zero headroom, third failed
// prefetch). Kept: parallel combine (waves 1-3 write cbuf[w-1] concurrently,
// ONE barrier, w0 sums) — no liveness extension, LDS-only cost.
// 4 waves/SIMD is the occupancy ceiling for this state size (R10/R17).
#define TILE_BODY(KBASE, DIAG)                                                          \
  {                                                                                     \
    int kbase = (KBASE);                                                                \
    short8 kf[4];                                                                       \
    _Pragma("unroll") for (int d0 = 0; d0 < 4; ++d0)                                    \
      kf[d0] = *reinterpret_cast<const short8*>(                                        \
          &Kb[(size_t)(kbase + ql) * HD + d0 * 16 + hi * 8]);                           \
    f32x16 sacc;                                                                        \
    _Pragma("unroll") for (int r = 0; r < 16; ++r) sacc[r] = 0.f;                       \
    __builtin_amdgcn_s_setprio(1);                                                      \
    _Pragma("unroll") for (int d0 = 0; d0 < 4; ++d0) sacc = mfma32(kf[d0], qf[d0], sacc); \
    __builtin_amdgcn_s_setprio(0);                                                      \
    const u16* Vtile = Vb + (size_t)(kbase >> 5) * 2048;                                \
    short8 vf[2][2];                                                                    \
    _Pragma("unroll") for (int c = 0; c < 2; ++c)                                       \
      _Pragma("unroll") for (int dh = 0; dh < 2; ++dh)                                  \
        vf[c][dh] = *reinterpret_cast<const short8*>(                                   \
            &Vtile[(dh * 32 + ql) * 32 + c * 16 + hi * 8]);                             \
    float p[16];                                                                        \
    _Pragma("unroll") for (int r2 = 0; r2 < 8; ++r2) {                                  \
      f32x2 s2 = {sacc[2 * r2], sacc[2 * r2 + 1]};                                      \
      f32x2 t2 = s2 * s2;                                                               \
      f32x2 u2 = __builtin_elementwise_fma(t2, C52, C32);                               \
      u2 = __builtin_elementwise_fma(t2, u2, L2E2);                                     \
      f32x2 v2 = s2 * u2;                                                               \
      float p0 = __builtin_amdgcn_exp2f(v2.x);                                          \
      float p1 = __builtin_amdgcn_exp2f(v2.y);                                          \
      if (DIAG) {                                                                       \
        int r = 2 * r2;                                                                 \
        int kpos0 = kbase + (r & 3) + 8 * (r >> 2) + 4 * hi;                            \
        int kpos1 = kbase + ((r + 1) & 3) + 8 * ((r + 1) >> 2) + 4 * hi;                \
        if (kpos0 > qbase + ql) p0 = 0.f;                                               \
        if (kpos1 > qbase + ql) p1 = 0.f;                                               \
      }                                                                                 \
      p[2 * r2] = p0;                                                                   \
      p[2 * r2 + 1] = p1;                                                               \
      lsum2 += (f32x2){p0, p1};                                                         \
    }                                                                                   \
    short8 pfrag[2];                                                                    \
    _Pragma("unroll") for (int c = 0; c < 2; ++c) {                                     \
      unsigned int a0, a1, b0, b1;                                                      \
      asm("v_cvt_pk_bf16_f32 %0, %1, %2" : "=v"(a0) : "v"(p[8 * c + 0]), "v"(p[8 * c + 1])); \
      asm("v_cvt_pk_bf16_f32 %0, %1, %2" : "=v"(a1) : "v"(p[8 * c + 2]), "v"(p[8 * c + 3])); \
      asm("v_cvt_pk_bf16_f32 %0, %1, %2" : "=v"(b0) : "v"(p[8 * c + 4]), "v"(p[8 * c + 5])); \
      asm("v_cvt_pk_bf16_f32 %0, %1, %2" : "=v"(b1) : "v"(p[8 * c + 6]), "v"(p[8 * c + 7])); \
      asm("v_permlane32_swap_b32 %0, %1" : "+v"(a0), "+v"(b0));                         \
      asm("v_permlane32_swap_b32 %0, %1" : "+v"(a1), "+v"(b1));                         \
      union { unsigned int u[4]; short8 s8; } pk;                                       \
      pk.u[0] = a0; pk.u[1] = a1; pk.u[2] = b0; pk.u[3] = b1;                           \
      pfrag[c] = pk.s8;                                                                 \
    }                                                                                   \
    __builtin_amdgcn_s_setprio(1);                                                      \
    _Pragma("unroll") for (int c = 0; c < 2; ++c) {                                     \
      xacc0 = mfma32(pfrag[c], vf[c][0], xacc0);                                        \
      xacc1 = mfma32(pfrag[c], vf[c][1], xacc1);                                        \
    }                                                                                   \
    __builtin_amdgcn_s_setprio(0);                                                      \
  }

__global__ __launch_bounds__(256, 4) void k_attn(const u16* __restrict__ Q,
                                                 const u16* __restrict__ K,
                                                 const u16* __restrict__ Vt,
                                                 u16* __restrict__ X) {
  int lin = blockIdx.x;          // 0..1023
  int xcd = lin & 7;             // dispatch round-robins XCDs
  int jj = lin >> 3;             // 0..127
  int bh = xcd * 4 + (jj & 3);   // 4 heads per XCD -> K+V 2MB/XCD, L2-resident
  int iq = jj >> 2;              // 0..31
  int tid = threadIdx.x, lane = tid & 63, w = tid >> 6;
  int ql = lane & 31, hi = lane >> 5;
  const u16* Qb = Q + (size_t)bh * SEQ * HD;
  const u16* Kb = K + (size_t)bh * SEQ * HD;
  const u16* Vb = Vt + (size_t)bh * HD * SEQ;
  int b = bh >> 4, h = bh & 15;
  size_t ob = (size_t)b * SEQ * DM + (size_t)h * HD;

  __shared__ float cbuf[3][64][34];  // parallel combine: one slice per wave 1..3

  const float L2E = 1.4426950408889634f;
  const f32x2 C32 = {-1.9235933878519513e-4f, -1.9235933878519513e-4f};  // -L2E/7500
  const f32x2 C52 = {3.0777494205630686e-8f, 3.0777494205630686e-8f};    // 2*L2E/(15*50^4)
  const f32x2 L2E2 = {L2E, L2E};

  for (int half = 0; half < 2; ++half) {
    int qc = half ? iq : 63 - iq;  // pair sums to 65 tiles -> uniform blocks
    int qbase = qc * 32;

    // Q fragments (B-operand): Q[qbase+ql][d0*16 + hi*8 .. +8]
    short8 qf[4];
#pragma unroll
    for (int d0 = 0; d0 < 4; ++d0)
      qf[d0] = *reinterpret_cast<const short8*>(&Qb[(size_t)(qbase + ql) * HD + d0 * 16 + hi * 8]);

    f32x16 xacc0, xacc1;
#pragma unroll
    for (int r = 0; r < 16; ++r) { xacc0[r] = 0.f; xacc1[r] = 0.f; }
    f32x2 lsum2 = {0.f, 0.f};

    // main tiles (kt < qc): mask compiled out.  diag tile (kt == qc):
    // owned by wave (qc & 3), mask active.
    for (int kt = w; kt < qc; kt += 4) TILE_BODY(kt * 32, false)
    if ((qc & 3) == w) TILE_BODY(qc * 32, true)

    float lsum = lsum2.x + lsum2.y;

    // ---- parallel combine of 4 waves' partials (plain sums; M=0 softmax) ----
    if (w > 0) {
#pragma unroll
      for (int r = 0; r < 16; ++r) {
        cbuf[w - 1][lane][r] = xacc0[r];
        cbuf[w - 1][lane][16 + r] = xacc1[r];
      }
      cbuf[w - 1][lane][32] = lsum;
    }
    __syncthreads();

    if (w == 0) {
#pragma unroll
      for (int s = 0; s < 3; ++s) {
#pragma unroll
        for (int r = 0; r < 16; ++r) {
          xacc0[r] += cbuf[s][lane][r];
          xacc1[r] += cbuf[s][lane][16 + r];
        }
        lsum += cbuf[s][lane][32];
      }
      // lanes q and q+32 hold the two k-half partials of row q
      lsum += __shfl_xor(lsum, 32, 64);
      float rinv = __builtin_amdgcn_rcpf(lsum);  // valid for q = ql on every lane

#pragma unroll
      for (int r = 0; r < 16; ++r) {
        int qrel = (r & 3) + 8 * (r >> 2) + 4 * hi;
        float rv = __shfl(rinv, qrel, 64);
        size_t row = ob + (size_t)(qbase + qrel) * DM;
        X[row + ql] = f2bf(xacc0[r] * rv);
        X[row + 32 + ql] = f2bf(xacc1[r] * rv);
      }
    }
    __syncthreads();  // cbuf safe for reuse by next half
  }
}

extern "C" void kernel_launch(void* const* d_in, const int* in_sizes, int n_in,
                              void* d_out, int out_size, void* d_ws, size_t ws_size,
                              hipStream_t stream) {
  const float* inputs = (const float*)d_in[0];
  const int* segpos = (const int*)d_in[1];
  // d_in[2] = mask: causal tril, known analytically — unused.
  const float* w_in = (const float*)d_in[3];
  const float* w_out = (const float*)d_in[4];
  float* out = (float*)d_out;
  char* ws = (char*)d_ws;

  size_t o = 0;
  u16* Xbf = (u16*)(ws + o); o += (size_t)4096 * 1024 * 2;   // inputs bf16; reused as attn output
  u16* WinT = (u16*)(ws + o); o += (size_t)3072 * 1024 * 2;  // w_in^T bf16
  u16* WoutT = (u16*)(ws + o); o += (size_t)1024 * 1024 * 2; // w_out^T bf16
  u16* Qb = (u16*)(ws + o); o += (size_t)NBATCH * NH * SEQ * HD * 2;
  u16* Kb = (u16*)(ws + o); o += (size_t)NBATCH * NH * SEQ * HD * 2;
  u16* Vt = (u16*)(ws + o); o += (size_t)NBATCH * NH * HD * SEQ * 2;
  float2* SC = (float2*)(ws + o); o += (size_t)SEQ * 32 * sizeof(float2);

  k_prep<<<8448, 256, 0, stream>>>(inputs, Xbf, w_in, WinT, w_out, WoutT, SC);
  k_gemm<0><<<dim3(24, 32), 256, 0, stream>>>(Xbf, WinT, 3072, Qb, Kb, Vt, nullptr);
  k_rope<<<512, 256, 0, stream>>>(Qb, Kb, segpos, SC);
  k_attn<<<1024, 256, 0, stream>>>(Qb, Kb, Vt, Xbf);
  k_gemm<1><<<dim3(8, 32), 256, 0, stream>>>(Xbf, WoutT, 1024, nullptr, nullptr, nullptr, out);
}

// Round 19
// 126.283 us; speedup vs baseline: 1.2493x; 1.2294x over previous
//
#include <hip/hip_runtime.h>
#include <hip/hip_bf16.h>

typedef unsigned short u16;
typedef __attribute__((ext_vector_type(8))) short short8;
typedef __attribute__((ext_vector_type(2))) float f32x2;
typedef __attribute__((ext_vector_type(4))) float f32x4;
typedef __attribute__((ext_vector_type(16))) float f32x16;

#define NH 16
#define HD 64
#define SEQ 2048
#define NBATCH 2
#define DM 1024

#define GLOAD_LDS(g, l)                                                              \
  __builtin_amdgcn_global_load_lds((__attribute__((address_space(1))) const void*)(g), \
                                   (__attribute__((address_space(3))) void*)(l), 16, 0, 0)

__device__ __forceinline__ u16 f2bf(float f) {
  __hip_bfloat16 h = __float2bfloat16(f);
  return *reinterpret_cast<u16*>(&h);
}
__device__ __forceinline__ float bf2f(u16 u) {
  union { unsigned int i; float f; } v; v.i = ((unsigned int)u) << 16; return v.f;
}
__device__ __forceinline__ f32x4 mfma16(short8 a, short8 b, f32x4 c) {
  return __builtin_amdgcn_mfma_f32_16x16x32_bf16(a, b, c, 0, 0, 0);
}
__device__ __forceinline__ f32x16 mfma32(short8 a, short8 b, f32x16 c) {
  return __builtin_amdgcn_mfma_f32_32x32x16_bf16(a, b, c, 0, 0, 0);
}

// ---------------- fused prep: convert | transpose(w_in) | transpose(w_out) | sincos ----
// R15: 4 independent memory-bound kernels -> 1 dispatch (sectioned by blockIdx).
__global__ __launch_bounds__(256) void k_prep(const float* __restrict__ inputs,
                                              u16* __restrict__ Xbf,
                                              const float* __restrict__ w_in,
                                              u16* __restrict__ WinT,
                                              const float* __restrict__ w_out,
                                              u16* __restrict__ WoutT,
                                              float2* __restrict__ SC) {
  __shared__ float t[32][33];
  int blk = blockIdx.x, tid = threadIdx.x;
  if (blk < 4096) {
    // f32 -> bf16 convert (4M floats as 1M float4)
    int i = blk * 256 + tid;
    float4 v = reinterpret_cast<const float4*>(inputs)[i];
    union { u16 h[4]; unsigned long long u; } o;
    o.h[0] = f2bf(v.x); o.h[1] = f2bf(v.y); o.h[2] = f2bf(v.z); o.h[3] = f2bf(v.w);
    reinterpret_cast<unsigned long long*>(Xbf)[i] = o.u;
  } else if (blk < 4096 + 3072 + 1024) {
    // f32 [R][C] -> bf16 [C][R] transpose (w_in: 1024x3072; w_out: 1024x1024)
    const float* src; u16* dst; int C, bx, by;
    if (blk < 4096 + 3072) {
      int b2 = blk - 4096; src = w_in; dst = WinT; C = 3072; bx = b2 % 96; by = b2 / 96;
    } else {
      int b2 = blk - (4096 + 3072); src = w_out; dst = WoutT; C = 1024; bx = b2 & 31; by = b2 >> 5;
    }
    const int R = 1024;
    int c0 = bx * 32, r0 = by * 32;
    int tx = tid & 31, ty = tid >> 5;
#pragma unroll
    for (int i = 0; i < 4; ++i)
      t[ty + 8 * i][tx] = src[(size_t)(r0 + ty + 8 * i) * C + c0 + tx];
    __syncthreads();
#pragma unroll
    for (int i = 0; i < 4; ++i)
      dst[(size_t)(c0 + ty + 8 * i) * R + r0 + tx] = f2bf(t[tx][ty + 8 * i]);
  } else {
    // RoPE sin/cos table: [pos][i] -> (sin, cos), 2048*32 entries
    int idx = (blk - 8192) * 256 + tid;
    int p = idx >> 5, i = idx & 31;
    const float l2ts = 0.41524101186092029f;  // log2(10000)/32
    float inv = exp2f(-(float)i * l2ts);      // 10000^(-i/32)
    float arg = (float)p * inv;
    float s, c;
    sincosf(arg, &s, &c);
    SC[idx] = make_float2(s, c);
  }
}

// ---------------- RoPE: Q in-place (rows, scaled 1/8); K -> Kf FRAGMENT order ----
// R19: attn's K loads were 32-distinct-line strided gathers per instruction
// (row = one 128B line); repacking K into MFMA-fragment order
// [tile][d0][lane*8elems] makes every attn K-load a contiguous 1KB (8 lines).
// K half is wave-per-tile: strided raw reads (one-shot), rope in-register,
// coalesced fragment stores.
__global__ __launch_bounds__(256) void k_rope(u16* __restrict__ Q, const u16* __restrict__ Kraw,
                                              u16* __restrict__ Kf,
                                              const int* __restrict__ segpos,
                                              const float2* __restrict__ sc) {
  int blk = blockIdx.x, tid = threadIdx.x;
  if (blk < 256) {
    // ---- Q rows, in-place, as before ----
    int r = blk * 256 + tid;  // 0..65535 = B*H*S
    int b = r >> 15;
    int s = r & (SEQ - 1);
    int pos = segpos[b * SEQ + s];
    const float2* scp = sc + (size_t)pos * 32;
    u16* row = Q + (size_t)r * HD;
    uint4 v[8];
#pragma unroll
    for (int i = 0; i < 8; ++i) v[i] = reinterpret_cast<uint4*>(row)[i];
    u16* e = reinterpret_cast<u16*>(v);
#pragma unroll
    for (int i = 0; i < 32; ++i) {
      float a = bf2f(e[i]), bq = bf2f(e[i + 32]);
      float2 t = scp[i];
      e[i] = f2bf((a * t.y - bq * t.x) * 0.125f);
      e[i + 32] = f2bf((bq * t.y + a * t.x) * 0.125f);
    }
#pragma unroll
    for (int i = 0; i < 8; ++i) reinterpret_cast<uint4*>(row)[i] = v[i];
  } else {
    // ---- K tiles: rope + fragment repack. wave-per-tile, 2 tiles/wave ----
    int wid = (blk - 256) * 4 + (tid >> 6);  // 0..1023
    int lane = tid & 63, ql = lane & 31, hi = lane >> 5;
#pragma unroll
    for (int t2 = 0; t2 < 2; ++t2) {
      int t = wid * 2 + t2;       // 0..2047
      int bh = t >> 6, kt = t & 63;
      int b = bh >> 4;
      int r = kt * 32 + ql;
      int pos = segpos[b * SEQ + r];
      const u16* src = Kraw + ((size_t)bh * SEQ + r) * HD + hi * 8;
      short8 ch[4];
#pragma unroll
      for (int d0 = 0; d0 < 4; ++d0)
        ch[d0] = *reinterpret_cast<const short8*>(src + d0 * 16);
      const float2* scp = sc + (size_t)pos * 32 + hi * 8;
#pragma unroll
      for (int d0 = 0; d0 < 2; ++d0)
#pragma unroll
        for (int e = 0; e < 8; ++e) {
          float2 tt = scp[d0 * 16 + e];  // index i = d0*16 + hi*8 + e
          float a = bf2f(((u16*)&ch[d0])[e]);
          float bb = bf2f(((u16*)&ch[d0 + 2])[e]);
          ((u16*)&ch[d0])[e] = f2bf(a * tt.y - bb * tt.x);
          ((u16*)&ch[d0 + 2])[e] = f2bf(bb * tt.y + a * tt.x);
        }
      u16* dst = Kf + (size_t)bh * SEQ * HD + (size_t)kt * 2048 + lane * 8;
#pragma unroll
      for (int d0 = 0; d0 < 4; ++d0)
        *reinterpret_cast<short8*>(dst + d0 * 512) = ch[d0];
    }
  }
}

// ---------------- bf16 MFMA GEMM, 128x128 tile, BK=64, global_load_lds ----------------
// A [M][1024] row-major bf16; Bt [N][1024] row-major bf16 (= B^T).
// T2 XOR-swizzle, both-sides-or-neither form (R14: conflicts 9.4M -> ~0).
// MODE 0: epilogue scatters in_proj into Q/K rows [b][h][s][64] and V in
//         FRAGMENT order (R19): off = kt*2048 + (kv>>4)*1024 + (d>>5)*512
//         + ((kv>>3)&1)*256 + (d&31)*8 + (kv&7)  — attn V-loads become
//         contiguous 1KB per instruction.
// MODE 1: plain f32 store to out [M][N].
// XCD-aware block swizzle (T1): grid sizes 768/256 are %8==0 -> bijective.
template <int MODE>
__global__ __launch_bounds__(256) void k_gemm(const u16* __restrict__ A, const u16* __restrict__ Bt,
                                              int N, u16* __restrict__ q, u16* __restrict__ kk,
                                              u16* __restrict__ vt, float* __restrict__ out) {
  __shared__ alignas(16) u16 As[128][64];
  __shared__ alignas(16) u16 Bs[128][64];
  const int K = 1024;
  int tid = threadIdx.x;
  int lane = tid & 63, w = tid >> 6;
  int wr = w >> 1, wc = w & 1;
  int col = lane & 15, grp = lane >> 4;
  int cx = col & 7;  // = row&7 of every fragment row this lane reads
  int bid = blockIdx.y * gridDim.x + blockIdx.x;
  int qq = (gridDim.x * gridDim.y) >> 3;
  int swz = (bid & 7) * qq + (bid >> 3);
  int m0 = (swz / gridDim.x) * 128;
  int n0 = (swz % gridDim.x) * 128;
  int crow = lane >> 3;
  int ccol = ((lane & 7) ^ (lane >> 3)) * 8;
  f32x4 zero4 = {0.f, 0.f, 0.f, 0.f};
  f32x4 acc[4][4];
#pragma unroll
  for (int i = 0; i < 4; ++i)
#pragma unroll
    for (int j = 0; j < 4; ++j) acc[i][j] = zero4;

  for (int k0 = 0; k0 < K; k0 += 64) {
    __syncthreads();  // previous compute done before overwrite
#pragma unroll
    for (int c = 0; c < 4; ++c) {
      int chunk = w * 4 + c;
      int r = chunk * 8 + crow;
      GLOAD_LDS(&A[(size_t)(m0 + r) * K + k0 + ccol], &As[0][0] + chunk * 512);
      GLOAD_LDS(&Bt[(size_t)(n0 + r) * K + k0 + ccol], &Bs[0][0] + chunk * 512);
    }
    __syncthreads();  // vmcnt drained by barrier -> tiles visible
#pragma unroll
    for (int kf = 0; kf < 2; ++kf) {
      short8 af[4], bfr[4];
      int sw = ((kf * 4 + grp) ^ cx) * 8;  // swizzled read column (elems)
#pragma unroll
      for (int i = 0; i < 4; ++i)
        af[i] = *reinterpret_cast<const short8*>(&As[wr * 64 + i * 16 + col][sw]);
#pragma unroll
      for (int i = 0; i < 4; ++i)
        bfr[i] = *reinterpret_cast<const short8*>(&Bs[wc * 64 + i * 16 + col][sw]);
#pragma unroll
      for (int mi = 0; mi < 4; ++mi)
#pragma unroll
        for (int ni = 0; ni < 4; ++ni) acc[mi][ni] = mfma16(af[mi], bfr[ni], acc[mi][ni]);
    }
  }
#pragma unroll
  for (int mi = 0; mi < 4; ++mi)
#pragma unroll
    for (int ni = 0; ni < 4; ++ni)
#pragma unroll
      for (int j = 0; j < 4; ++j) {
        int m = m0 + wr * 64 + mi * 16 + grp * 4 + j;
        int n = n0 + wc * 64 + ni * 16 + col;
        float v = acc[mi][ni][j];
        if (MODE == 0) {
          int b = m >> 11, s = m & 2047;
          int h = n / 192, f = n - h * 192;
          u16 bv = f2bf(v);
          if (f < 64)
            q[(((size_t)(b * NH + h) * SEQ + s) << 6) + f] = bv;
          else if (f < 128)
            kk[(((size_t)(b * NH + h) * SEQ + s) << 6) + (f - 64)] = bv;
          else {
            int d = f - 128, kv = s & 31;
            vt[(size_t)(b * NH + h) * (HD * SEQ) + (size_t)(s >> 5) * 2048 +
               ((kv >> 4) << 10) + ((d >> 5) << 9) + (((kv >> 3) & 1) << 8) +
               ((d & 31) << 3) + (kv & 7)] = bv;
          }
        } else {
          out[(size_t)m * N + n] = v;
        }
      }
}

// ---------------- flash attention, causal, softcap 50 ----------------
// R9 structure: 4-wave blocks, grid 1024, uniform-work pairing (63-i, i),
// split-KV x4, parallel combine (R18). Packed-f32 softmax (R11). Raw exp2 +
// diag peel (R16). R19: K and V read from FRAGMENT-ORDER buffers — every
// K/V load is a contiguous 1KB (8 lines once) instead of 32 strided lines;
// per-tile TA line-accesses 256 -> 64 (R18 accounting: TA was ~50% of the
// cycle budget). No prefetch (R8/R12/R17 all spilled: arch64+AGPR64 = cap).
#define TILE_BODY(KBASE, DIAG)                                                          \
  {                                                                                     \
    int kbase = (KBASE);                                                                \
    const u16* Ktile = Kb + (size_t)(kbase >> 5) * 2048;                                \
    short8 kf[4];                                                                       \
    _Pragma("unroll") for (int d0 = 0; d0 < 4; ++d0)                                    \
      kf[d0] = *reinterpret_cast<const short8*>(&Ktile[d0 * 512 + lane * 8]);           \
    f32x16 sacc;                                                                        \
    _Pragma("unroll") for (int r = 0; r < 16; ++r) sacc[r] = 0.f;                       \
    __builtin_amdgcn_s_setprio(1);                                                      \
    _Pragma("unroll") for (int d0 = 0; d0 < 4; ++d0) sacc = mfma32(kf[d0], qf[d0], sacc); \
    __builtin_amdgcn_s_setprio(0);                                                      \
    const u16* Vtile = Vb + (size_t)(kbase >> 5) * 2048;                                \
    short8 vf[2][2];                                                                    \
    _Pragma("unroll") for (int c = 0; c < 2; ++c)                                       \
      _Pragma("unroll") for (int dh = 0; dh < 2; ++dh)                                  \
        vf[c][dh] = *reinterpret_cast<const short8*>(                                   \
            &Vtile[(c * 2 + dh) * 512 + lane * 8]);                                     \
    float p[16];                                                                        \
    _Pragma("unroll") for (int r2 = 0; r2 < 8; ++r2) {                                  \
      f32x2 s2 = {sacc[2 * r2], sacc[2 * r2 + 1]};                                      \
      f32x2 t2 = s2 * s2;                                                               \
      f32x2 u2 = __builtin_elementwise_fma(t2, C52, C32);                               \
      u2 = __builtin_elementwise_fma(t2, u2, L2E2);                                     \
      f32x2 v2 = s2 * u2;                                                               \
      float p0 = __builtin_amdgcn_exp2f(v2.x);                                          \
      float p1 = __builtin_amdgcn_exp2f(v2.y);                                          \
      if (DIAG) {                                                                       \
        int r = 2 * r2;                                                                 \
        int kpos0 = kbase + (r & 3) + 8 * (r >> 2) + 4 * hi;                            \
        int kpos1 = kbase + ((r + 1) & 3) + 8 * ((r + 1) >> 2) + 4 * hi;                \
        if (kpos0 > qbase + ql) p0 = 0.f;                                               \
        if (kpos1 > qbase + ql) p1 = 0.f;                                               \
      }                                                                                 \
      p[2 * r2] = p0;                                                                   \
      p[2 * r2 + 1] = p1;                                                               \
      lsum2 += (f32x2){p0, p1};                                                         \
    }                                                                                   \
    short8 pfrag[2];                                                                    \
    _Pragma("unroll") for (int c = 0; c < 2; ++c) {                                     \
      unsigned int a0, a1, b0, b1;                                                      \
      asm("v_cvt_pk_bf16_f32 %0, %1, %2" : "=v"(a0) : "v"(p[8 * c + 0]), "v"(p[8 * c + 1])); \
      asm("v_cvt_pk_bf16_f32 %0, %1, %2" : "=v"(a1) : "v"(p[8 * c + 2]), "v"(p[8 * c + 3])); \
      asm("v_cvt_pk_bf16_f32 %0, %1, %2" : "=v"(b0) : "v"(p[8 * c + 4]), "v"(p[8 * c + 5])); \
      asm("v_cvt_pk_bf16_f32 %0, %1, %2" : "=v"(b1) : "v"(p[8 * c + 6]), "v"(p[8 * c + 7])); \
      asm("v_permlane32_swap_b32 %0, %1" : "+v"(a0), "+v"(b0));                         \
      asm("v_permlane32_swap_b32 %0, %1" : "+v"(a1), "+v"(b1));                         \
      union { unsigned int u[4]; short8 s8; } pk;                                       \
      pk.u[0] = a0; pk.u[1] = a1; pk.u[2] = b0; pk.u[3] = b1;                           \
      pfrag[c] = pk.s8;                                                                 \
    }                                                                                   \
    __builtin_amdgcn_s_setprio(1);                                                      \
    _Pragma("unroll") for (int c = 0; c < 2; ++c) {                                     \
      xacc0 = mfma32(pfrag[c], vf[c][0], xacc0);                                        \
      xacc1 = mfma32(pfrag[c], vf[c][1], xacc1);                                        \
    }                                                                                   \
    __builtin_amdgcn_s_setprio(0);                                                      \
  }

__global__ __launch_bounds__(256, 4) void k_attn(const u16* __restrict__ Q,
                                                 const u16* __restrict__ Kf,
                                                 const u16* __restrict__ Vt,
                                                 u16* __restrict__ X) {
  int lin = blockIdx.x;          // 0..1023
  int xcd = lin & 7;             // dispatch round-robins XCDs
  int jj = lin >> 3;             // 0..127
  int bh = xcd * 4 + (jj & 3);   // 4 heads per XCD -> K+V 2MB/XCD, L2-resident
  int iq = jj >> 2;              // 0..31
  int tid = threadIdx.x, lane = tid & 63, w = tid >> 6;
  int ql = lane & 31, hi = lane >> 5;
  const u16* Qb = Q + (size_t)bh * SEQ * HD;
  const u16* Kb = Kf + (size_t)bh * SEQ * HD;
  const u16* Vb = Vt + (size_t)bh * HD * SEQ;
  int b = bh >> 4, h = bh & 15;
  size_t ob = (size_t)b * SEQ * DM + (size_t)h * HD;

  __shared__ float cbuf[3][64][34];  // parallel combine: one slice per wave 1..3

  const float L2E = 1.4426950408889634f;
  const f32x2 C32 = {-1.9235933878519513e-4f, -1.9235933878519513e-4f};  // -L2E/7500
  const f32x2 C52 = {3.0777494205630686e-8f, 3.0777494205630686e-8f};    // 2*L2E/(15*50^4)
  const f32x2 L2E2 = {L2E, L2E};

  for (int half = 0; half < 2; ++half) {
    int qc = half ? iq : 63 - iq;  // pair sums to 65 tiles -> uniform blocks
    int qbase = qc * 32;

    // Q fragments (B-operand): Q[qbase+ql][d0*16 + hi*8 .. +8]
    short8 qf[4];
#pragma unroll
    for (int d0 = 0; d0 < 4; ++d0)
      qf[d0] = *reinterpret_cast<const short8*>(&Qb[(size_t)(qbase + ql) * HD + d0 * 16 + hi * 8]);

    f32x16 xacc0, xacc1;
#pragma unroll
    for (int r = 0; r < 16; ++r) { xacc0[r] = 0.f; xacc1[r] = 0.f; }
    f32x2 lsum2 = {0.f, 0.f};

    // main tiles (kt < qc): mask compiled out.  diag tile (kt == qc):
    // owned by wave (qc & 3), mask active.
    for (int kt = w; kt < qc; kt += 4) TILE_BODY(kt * 32, false)
    if ((qc & 3) == w) TILE_BODY(qc * 32, true)

    float lsum = lsum2.x + lsum2.y;

    // ---- parallel combine of 4 waves' partials (plain sums; M=0 softmax) ----
    if (w > 0) {
#pragma unroll
      for (int r = 0; r < 16; ++r) {
        cbuf[w - 1][lane][r] = xacc0[r];
        cbuf[w - 1][lane][16 + r] = xacc1[r];
      }
      cbuf[w - 1][lane][32] = lsum;
    }
    __syncthreads();

    if (w == 0) {
#pragma unroll
      for (int s = 0; s < 3; ++s) {
#pragma unroll
        for (int r = 0; r < 16; ++r) {
          xacc0[r] += cbuf[s][lane][r];
          xacc1[r] += cbuf[s][lane][16 + r];
        }
        lsum += cbuf[s][lane][32];
      }
      // lanes q and q+32 hold the two k-half partials of row q
      lsum += __shfl_xor(lsum, 32, 64);
      float rinv = __builtin_amdgcn_rcpf(lsum);  // valid for q = ql on every lane

#pragma unroll
      for (int r = 0; r < 16; ++r) {
        int qrel = (r & 3) + 8 * (r >> 2) + 4 * hi;
        float rv = __shfl(rinv, qrel, 64);
        size_t row = ob + (size_t)(qbase + qrel) * DM;
        X[row + ql] = f2bf(xacc0[r] * rv);
        X[row + 32 + ql] = f2bf(xacc1[r] * rv);
      }
    }
    __syncthreads();  // cbuf safe for reuse by next half
  }
}

extern "C" void kernel_launch(void* const* d_in, const int* in_sizes, int n_in,
                              void* d_out, int out_size, void* d_ws, size_t ws_size,
                              hipStream_t stream) {
  const float* inputs = (const float*)d_in[0];
  const int* segpos = (const int*)d_in[1];
  // d_in[2] = mask: causal tril, known analytically — unused.
  const float* w_in = (const float*)d_in[3];
  const float* w_out = (const float*)d_in[4];
  float* out = (float*)d_out;
  char* ws = (char*)d_ws;

  size_t o = 0;
  u16* Xbf = (u16*)(ws + o); o += (size_t)4096 * 1024 * 2;   // inputs bf16; reused as attn output
  u16* WinT = (u16*)(ws + o); o += (size_t)3072 * 1024 * 2;  // w_in^T bf16
  u16* WoutT = (u16*)(ws + o); o += (size_t)1024 * 1024 * 2; // w_out^T bf16
  u16* Qb = (u16*)(ws + o); o += (size_t)NBATCH * NH * SEQ * HD * 2;
  u16* Kb = (u16*)(ws + o); o += (size_t)NBATCH * NH * SEQ * HD * 2;  // raw K (gemm out)
  u16* Kf = (u16*)(ws + o); o += (size_t)NBATCH * NH * SEQ * HD * 2;  // fragment K (rope out)
  u16* Vt = (u16*)(ws + o); o += (size_t)NBATCH * NH * HD * SEQ * 2;  // fragment V
  float2* SC = (float2*)(ws + o); o += (size_t)SEQ * 32 * sizeof(float2);

  k_prep<<<8448, 256, 0, stream>>>(inputs, Xbf, w_in, WinT, w_out, WoutT, SC);
  k_gemm<0><<<dim3(24, 32), 256, 0, stream>>>(Xbf, WinT, 3072, Qb, Kb, Vt, nullptr);
  k_rope<<<512, 256, 0, stream>>>(Qb, Kb, Kf, segpos, SC);
  k_attn<<<1024, 256, 0, stream>>>(Qb, Kf, Vt, Xbf);
  k_gemm<1><<<dim3(8, 32), 256, 0, stream>>>(Xbf, WoutT, 1024, nullptr, nullptr, nullptr, out);
}

// Round 20
// 113.193 us; speedup vs baseline: 1.3938x; 1.1156x over previous
//
#include <hip/hip_runtime.h>
#include <hip/hip_bf16.h>

typedef unsigned short u16;
typedef __attribute__((ext_vector_type(8))) short short8;
typedef __attribute__((ext_vector_type(2))) float f32x2;
typedef __attribute__((ext_vector_type(4))) float f32x4;
typedef __attribute__((ext_vector_type(16))) float f32x16;

#define NH 16
#define HD 64
#define SEQ 2048
#define NBATCH 2
#define DM 1024

#define GLOAD_LDS(g, l)                                                              \
  __builtin_amdgcn_global_load_lds((__attribute__((address_space(1))) const void*)(g), \
                                   (__attribute__((address_space(3))) void*)(l), 16, 0, 0)

__device__ __forceinline__ u16 f2bf(float f) {
  __hip_bfloat16 h = __float2bfloat16(f);
  return *reinterpret_cast<u16*>(&h);
}
__device__ __forceinline__ float bf2f(u16 u) {
  union { unsigned int i; float f; } v; v.i = ((unsigned int)u) << 16; return v.f;
}
__device__ __forceinline__ f32x4 mfma16(short8 a, short8 b, f32x4 c) {
  return __builtin_amdgcn_mfma_f32_16x16x32_bf16(a, b, c, 0, 0, 0);
}
__device__ __forceinline__ f32x16 mfma32(short8 a, short8 b, f32x16 c) {
  return __builtin_amdgcn_mfma_f32_32x32x16_bf16(a, b, c, 0, 0, 0);
}

// ---------------- fused prep: convert | transpose(w_in) | transpose(w_out) | sincos ----
// R15: 4 independent memory-bound kernels -> 1 dispatch (sectioned by blockIdx).
__global__ __launch_bounds__(256) void k_prep(const float* __restrict__ inputs,
                                              u16* __restrict__ Xbf,
                                              const float* __restrict__ w_in,
                                              u16* __restrict__ WinT,
                                              const float* __restrict__ w_out,
                                              u16* __restrict__ WoutT,
                                              float2* __restrict__ SC) {
  __shared__ float t[32][33];
  int blk = blockIdx.x, tid = threadIdx.x;
  if (blk < 4096) {
    // f32 -> bf16 convert (4M floats as 1M float4)
    int i = blk * 256 + tid;
    float4 v = reinterpret_cast<const float4*>(inputs)[i];
    union { u16 h[4]; unsigned long long u; } o;
    o.h[0] = f2bf(v.x); o.h[1] = f2bf(v.y); o.h[2] = f2bf(v.z); o.h[3] = f2bf(v.w);
    reinterpret_cast<unsigned long long*>(Xbf)[i] = o.u;
  } else if (blk < 4096 + 3072 + 1024) {
    // f32 [R][C] -> bf16 [C][R] transpose (w_in: 1024x3072; w_out: 1024x1024)
    const float* src; u16* dst; int C, bx, by;
    if (blk < 4096 + 3072) {
      int b2 = blk - 4096; src = w_in; dst = WinT; C = 3072; bx = b2 % 96; by = b2 / 96;
    } else {
      int b2 = blk - (4096 + 3072); src = w_out; dst = WoutT; C = 1024; bx = b2 & 31; by = b2 >> 5;
    }
    const int R = 1024;
    int c0 = bx * 32, r0 = by * 32;
    int tx = tid & 31, ty = tid >> 5;
#pragma unroll
    for (int i = 0; i < 4; ++i)
      t[ty + 8 * i][tx] = src[(size_t)(r0 + ty + 8 * i) * C + c0 + tx];
    __syncthreads();
#pragma unroll
    for (int i = 0; i < 4; ++i)
      dst[(size_t)(c0 + ty + 8 * i) * R + r0 + tx] = f2bf(t[tx][ty + 8 * i]);
  } else {
    // RoPE sin/cos table: [pos][i] -> (sin, cos), 2048*32 entries
    int idx = (blk - 8192) * 256 + tid;
    int p = idx >> 5, i = idx & 31;
    const float l2ts = 0.41524101186092029f;  // log2(10000)/32
    float inv = exp2f(-(float)i * l2ts);      // 10000^(-i/32)
    float arg = (float)p * inv;
    float s, c;
    sincosf(arg, &s, &c);
    SC[idx] = make_float2(s, c);
  }
}

// ---------------- RoPE: Q in-place (rows, scaled 1/8); K -> Kf FRAGMENT order ----
// R19: repack K into MFMA-fragment order [tile][d0][lane*8] so attn K-loads
// are contiguous 1KB. Wave-per-tile: strided raw reads, rope in-register,
// coalesced fragment stores.
__global__ __launch_bounds__(256) void k_rope(u16* __restrict__ Q, const u16* __restrict__ Kraw,
                                              u16* __restrict__ Kf,
                                              const int* __restrict__ segpos,
                                              const float2* __restrict__ sc) {
  int blk = blockIdx.x, tid = threadIdx.x;
  if (blk < 256) {
    // ---- Q rows, in-place ----
    int r = blk * 256 + tid;  // 0..65535 = B*H*S
    int b = r >> 15;
    int s = r & (SEQ - 1);
    int pos = segpos[b * SEQ + s];
    const float2* scp = sc + (size_t)pos * 32;
    u16* row = Q + (size_t)r * HD;
    uint4 v[8];
#pragma unroll
    for (int i = 0; i < 8; ++i) v[i] = reinterpret_cast<uint4*>(row)[i];
    u16* e = reinterpret_cast<u16*>(v);
#pragma unroll
    for (int i = 0; i < 32; ++i) {
      float a = bf2f(e[i]), bq = bf2f(e[i + 32]);
      float2 t = scp[i];
      e[i] = f2bf((a * t.y - bq * t.x) * 0.125f);
      e[i + 32] = f2bf((bq * t.y + a * t.x) * 0.125f);
    }
#pragma unroll
    for (int i = 0; i < 8; ++i) reinterpret_cast<uint4*>(row)[i] = v[i];
  } else {
    // ---- K tiles: rope + fragment repack. wave-per-tile, 2 tiles/wave ----
    int wid = (blk - 256) * 4 + (tid >> 6);  // 0..1023
    int lane = tid & 63, ql = lane & 31, hi = lane >> 5;
#pragma unroll
    for (int t2 = 0; t2 < 2; ++t2) {
      int t = wid * 2 + t2;       // 0..2047
      int bh = t >> 6, kt = t & 63;
      int b = bh >> 4;
      int r = kt * 32 + ql;
      int pos = segpos[b * SEQ + r];
      const u16* src = Kraw + ((size_t)bh * SEQ + r) * HD + hi * 8;
      short8 ch[4];
#pragma unroll
      for (int d0 = 0; d0 < 4; ++d0)
        ch[d0] = *reinterpret_cast<const short8*>(src + d0 * 16);
      const float2* scp = sc + (size_t)pos * 32 + hi * 8;
#pragma unroll
      for (int d0 = 0; d0 < 2; ++d0)
#pragma unroll
        for (int e = 0; e < 8; ++e) {
          float2 tt = scp[d0 * 16 + e];  // index i = d0*16 + hi*8 + e
          float a = bf2f(((u16*)&ch[d0])[e]);
          float bb = bf2f(((u16*)&ch[d0 + 2])[e]);
          ((u16*)&ch[d0])[e] = f2bf(a * tt.y - bb * tt.x);
          ((u16*)&ch[d0 + 2])[e] = f2bf(bb * tt.y + a * tt.x);
        }
      u16* dst = Kf + (size_t)bh * SEQ * HD + (size_t)kt * 2048 + lane * 8;
#pragma unroll
      for (int d0 = 0; d0 < 4; ++d0)
        *reinterpret_cast<short8*>(dst + d0 * 512) = ch[d0];
    }
  }
}

// ---------------- bf16 MFMA GEMM, 64x128 tile, BK=64, global_load_lds ----------------
// R20: M-tile halved 128->64. R19's profile: gemm<0> grid 768 = 3 blocks/CU
// = 37.5% occupancy cap (measured 14%) — grid-starved latency-bound kernel.
// Now gemm<0> = 1536 blocks (6/CU), gemm<1> = 512 (2/CU). LDS 24KB ->
// 6 blocks/CU fits. acc[2][4] = 32 AGPR. Staging 24 chunks = 6/wave.
// T2 XOR-swizzle both-sides form kept (R14); T1 XCD swizzle kept (grids
// 1536/512 %8==0). MODE 0 scatters Q/K rows + FRAGMENT-order V (R19).
template <int MODE>
__global__ __launch_bounds__(256) void k_gemm(const u16* __restrict__ A, const u16* __restrict__ Bt,
                                              int N, u16* __restrict__ q, u16* __restrict__ kk,
                                              u16* __restrict__ vt, float* __restrict__ out) {
  __shared__ alignas(16) u16 As[64][64];
  __shared__ alignas(16) u16 Bs[128][64];
  const int K = 1024;
  int tid = threadIdx.x;
  int lane = tid & 63, w = tid >> 6;
  int wr = w >> 1, wc = w & 1;
  int col = lane & 15, grp = lane >> 4;
  int cx = col & 7;  // = row&7 of every fragment row this lane reads
  int bid = blockIdx.y * gridDim.x + blockIdx.x;
  int qq = (gridDim.x * gridDim.y) >> 3;
  int swz = (bid & 7) * qq + (bid >> 3);
  int m0 = (swz / gridDim.x) * 64;
  int n0 = (swz % gridDim.x) * 128;
  // global_load_lds chunk geometry: chunk = 1KB = 8 rows of 64 bf16; lane
  // writes LDS bytes [chunk*1024 + lane*16) -> row chunk*8+(lane>>3).
  // T2 pre-swizzle: source column slot XOR'd with row&7 (= lane>>3).
  int crow = lane >> 3;
  int ccol = ((lane & 7) ^ (lane >> 3)) * 8;
  f32x4 zero4 = {0.f, 0.f, 0.f, 0.f};
  f32x4 acc[2][4];
#pragma unroll
  for (int i = 0; i < 2; ++i)
#pragma unroll
    for (int j = 0; j < 4; ++j) acc[i][j] = zero4;

  for (int k0 = 0; k0 < K; k0 += 64) {
    __syncthreads();  // previous compute done before overwrite
#pragma unroll
    for (int c = 0; c < 6; ++c) {
      int chunk = w * 6 + c;  // 0..23: A chunks 0..7, B chunks 8..23
      if (chunk < 8) {
        int r = chunk * 8 + crow;
        GLOAD_LDS(&A[(size_t)(m0 + r) * K + k0 + ccol], &As[0][0] + chunk * 512);
      } else {
        int r = (chunk - 8) * 8 + crow;
        GLOAD_LDS(&Bt[(size_t)(n0 + r) * K + k0 + ccol], &Bs[0][0] + (chunk - 8) * 512);
      }
    }
    __syncthreads();  // vmcnt drained by barrier -> tiles visible
#pragma unroll
    for (int kf = 0; kf < 2; ++kf) {
      short8 af[2], bfr[4];
      int sw = ((kf * 4 + grp) ^ cx) * 8;  // swizzled read column (elems)
#pragma unroll
      for (int i = 0; i < 2; ++i)
        af[i] = *reinterpret_cast<const short8*>(&As[wr * 32 + i * 16 + col][sw]);
#pragma unroll
      for (int i = 0; i < 4; ++i)
        bfr[i] = *reinterpret_cast<const short8*>(&Bs[wc * 64 + i * 16 + col][sw]);
#pragma unroll
      for (int mi = 0; mi < 2; ++mi)
#pragma unroll
        for (int ni = 0; ni < 4; ++ni) acc[mi][ni] = mfma16(af[mi], bfr[ni], acc[mi][ni]);
    }
  }
#pragma unroll
  for (int mi = 0; mi < 2; ++mi)
#pragma unroll
    for (int ni = 0; ni < 4; ++ni)
#pragma unroll
      for (int j = 0; j < 4; ++j) {
        int m = m0 + wr * 32 + mi * 16 + grp * 4 + j;
        int n = n0 + wc * 64 + ni * 16 + col;
        float v = acc[mi][ni][j];
        if (MODE == 0) {
          int b = m >> 11, s = m & 2047;
          int h = n / 192, f = n - h * 192;
          u16 bv = f2bf(v);
          if (f < 64)
            q[(((size_t)(b * NH + h) * SEQ + s) << 6) + f] = bv;
          else if (f < 128)
            kk[(((size_t)(b * NH + h) * SEQ + s) << 6) + (f - 64)] = bv;
          else {
            int d = f - 128, kv = s & 31;
            vt[(size_t)(b * NH + h) * (HD * SEQ) + (size_t)(s >> 5) * 2048 +
               ((kv >> 4) << 10) + ((d >> 5) << 9) + (((kv >> 3) & 1) << 8) +
               ((d & 31) << 3) + (kv & 7)] = bv;
          }
        } else {
          out[(size_t)m * N + n] = v;
        }
      }
}

// ---------------- flash attention, causal, softcap 50 ----------------
// R9 structure: 4-wave blocks, grid 1024, uniform-work pairing (63-i, i),
// split-KV x4, parallel combine (R18). Packed-f32 softmax (R11). Raw exp2 +
// diag peel (R16). Fragment-order K/V (R19: attn 58.6 -> <54, TA accounting
// confirmed). No prefetch (R8/R12/R17 all spilled: arch64+AGPR64 = cap).
#define TILE_BODY(KBASE, DIAG)                                                          \
  {                                                                                     \
    int kbase = (KBASE);                                                                \
    const u16* Ktile = Kb + (size_t)(kbase >> 5) * 2048;                                \
    short8 kf[4];                                                                       \
    _Pragma("unroll") for (int d0 = 0; d0 < 4; ++d0)                                    \
      kf[d0] = *reinterpret_cast<const short8*>(&Ktile[d0 * 512 + lane * 8]);           \
    f32x16 sacc;                                                                        \
    _Pragma("unroll") for (int r = 0; r < 16; ++r) sacc[r] = 0.f;                       \
    __builtin_amdgcn_s_setprio(1);                                                      \
    _Pragma("unroll") for (int d0 = 0; d0 < 4; ++d0) sacc = mfma32(kf[d0], qf[d0], sacc); \
    __builtin_amdgcn_s_setprio(0);                                                      \
    const u16* Vtile = Vb + (size_t)(kbase >> 5) * 2048;                                \
    short8 vf[2][2];                                                                    \
    _Pragma("unroll") for (int c = 0; c < 2; ++c)                                       \
      _Pragma("unroll") for (int dh = 0; dh < 2; ++dh)                                  \
        vf[c][dh] = *reinterpret_cast<const short8*>(                                   \
            &Vtile[(c * 2 + dh) * 512 + lane * 8]);                                     \
    float p[16];                                                                        \
    _Pragma("unroll") for (int r2 = 0; r2 < 8; ++r2) {                                  \
      f32x2 s2 = {sacc[2 * r2], sacc[2 * r2 + 1]};                                      \
      f32x2 t2 = s2 * s2;                                                               \
      f32x2 u2 = __builtin_elementwise_fma(t2, C52, C32);                               \
      u2 = __builtin_elementwise_fma(t2, u2, L2E2);                                     \
      f32x2 v2 = s2 * u2;                                                               \
      float p0 = __builtin_amdgcn_exp2f(v2.x);                                          \
      float p1 = __builtin_amdgcn_exp2f(v2.y);                                          \
      if (DIAG) {                                                                       \
        int r = 2 * r2;                                                                 \
        int kpos0 = kbase + (r & 3) + 8 * (r >> 2) + 4 * hi;                            \
        int kpos1 = kbase + ((r + 1) & 3) + 8 * ((r + 1) >> 2) + 4 * hi;                \
        if (kpos0 > qbase + ql) p0 = 0.f;                                               \
        if (kpos1 > qbase + ql) p1 = 0.f;                                               \
      }                                                                                 \
      p[2 * r2] = p0;                                                                   \
      p[2 * r2 + 1] = p1;                                                               \
      lsum2 += (f32x2){p0, p1};                                                         \
    }                                                                                   \
    short8 pfrag[2];                                                                    \
    _Pragma("unroll") for (int c = 0; c < 2; ++c) {                                     \
      unsigned int a0, a1, b0, b1;                                                      \
      asm("v_cvt_pk_bf16_f32 %0, %1, %2" : "=v"(a0) : "v"(p[8 * c + 0]), "v"(p[8 * c + 1])); \
      asm("v_cvt_pk_bf16_f32 %0, %1, %2" : "=v"(a1) : "v"(p[8 * c + 2]), "v"(p[8 * c + 3])); \
      asm("v_cvt_pk_bf16_f32 %0, %1, %2" : "=v"(b0) : "v"(p[8 * c + 4]), "v"(p[8 * c + 5])); \
      asm("v_cvt_pk_bf16_f32 %0, %1, %2" : "=v"(b1) : "v"(p[8 * c + 6]), "v"(p[8 * c + 7])); \
      asm("v_permlane32_swap_b32 %0, %1" : "+v"(a0), "+v"(b0));                         \
      asm("v_permlane32_swap_b32 %0, %1" : "+v"(a1), "+v"(b1));                         \
      union { unsigned int u[4]; short8 s8; } pk;                                       \
      pk.u[0] = a0; pk.u[1] = a1; pk.u[2] = b0; pk.u[3] = b1;                           \
      pfrag[c] = pk.s8;                                                                 \
    }                                                                                   \
    __builtin_amdgcn_s_setprio(1);                                                      \
    _Pragma("unroll") for (int c = 0; c < 2; ++c) {                                     \
      xacc0 = mfma32(pfrag[c], vf[c][0], xacc0);                                        \
      xacc1 = mfma32(pfrag[c], vf[c][1], xacc1);                                        \
    }                                                                                   \
    __builtin_amdgcn_s_setprio(0);                                                      \
  }

__global__ __launch_bounds__(256, 4) void k_attn(const u16* __restrict__ Q,
                                                 const u16* __restrict__ Kf,
                                                 const u16* __restrict__ Vt,
                                                 u16* __restrict__ X) {
  int lin = blockIdx.x;          // 0..1023
  int xcd = lin & 7;             // dispatch round-robins XCDs
  int jj = lin >> 3;             // 0..127
  int bh = xcd * 4 + (jj & 3);   // 4 heads per XCD -> K+V 2MB/XCD, L2-resident
  int iq = jj >> 2;              // 0..31
  int tid = threadIdx.x, lane = tid & 63, w = tid >> 6;
  int ql = lane & 31, hi = lane >> 5;
  const u16* Qb = Q + (size_t)bh * SEQ * HD;
  const u16* Kb = Kf + (size_t)bh * SEQ * HD;
  const u16* Vb = Vt + (size_t)bh * HD * SEQ;
  int b = bh >> 4, h = bh & 15;
  size_t ob = (size_t)b * SEQ * DM + (size_t)h * HD;

  __shared__ float cbuf[3][64][34];  // parallel combine: one slice per wave 1..3

  const float L2E = 1.4426950408889634f;
  const f32x2 C32 = {-1.9235933878519513e-4f, -1.9235933878519513e-4f};  // -L2E/7500
  const f32x2 C52 = {3.0777494205630686e-8f, 3.0777494205630686e-8f};    // 2*L2E/(15*50^4)
  const f32x2 L2E2 = {L2E, L2E};

  for (int half = 0; half < 2; ++half) {
    int qc = half ? iq : 63 - iq;  // pair sums to 65 tiles -> uniform blocks
    int qbase = qc * 32;

    // Q fragments (B-operand): Q[qbase+ql][d0*16 + hi*8 .. +8]
    short8 qf[4];
#pragma unroll
    for (int d0 = 0; d0 < 4; ++d0)
      qf[d0] = *reinterpret_cast<const short8*>(&Qb[(size_t)(qbase + ql) * HD + d0 * 16 + hi * 8]);

    f32x16 xacc0, xacc1;
#pragma unroll
    for (int r = 0; r < 16; ++r) { xacc0[r] = 0.f; xacc1[r] = 0.f; }
    f32x2 lsum2 = {0.f, 0.f};

    // main tiles (kt < qc): mask compiled out.  diag tile (kt == qc):
    // owned by wave (qc & 3), mask active.
    for (int kt = w; kt < qc; kt += 4) TILE_BODY(kt * 32, false)
    if ((qc & 3) == w) TILE_BODY(qc * 32, true)

    float lsum = lsum2.x + lsum2.y;

    // ---- parallel combine of 4 waves' partials (plain sums; M=0 softmax) ----
    if (w > 0) {
#pragma unroll
      for (int r = 0; r < 16; ++r) {
        cbuf[w - 1][lane][r] = xacc0[r];
        cbuf[w - 1][lane][16 + r] = xacc1[r];
      }
      cbuf[w - 1][lane][32] = lsum;
    }
    __syncthreads();

    if (w == 0) {
#pragma unroll
      for (int s = 0; s < 3; ++s) {
#pragma unroll
        for (int r = 0; r < 16; ++r) {
          xacc0[r] += cbuf[s][lane][r];
          xacc1[r] += cbuf[s][lane][16 + r];
        }
        lsum += cbuf[s][lane][32];
      }
      // lanes q and q+32 hold the two k-half partials of row q
      lsum += __shfl_xor(lsum, 32, 64);
      float rinv = __builtin_amdgcn_rcpf(lsum);  // valid for q = ql on every lane

#pragma unroll
      for (int r = 0; r < 16; ++r) {
        int qrel = (r & 3) + 8 * (r >> 2) + 4 * hi;
        float rv = __shfl(rinv, qrel, 64);
        size_t row = ob + (size_t)(qbase + qrel) * DM;
        X[row + ql] = f2bf(xacc0[r] * rv);
        X[row + 32 + ql] = f2bf(xacc1[r] * rv);
      }
    }
    __syncthreads();  // cbuf safe for reuse by next half
  }
}

extern "C" void kernel_launch(void* const* d_in, const int* in_sizes, int n_in,
                              void* d_out, int out_size, void* d_ws, size_t ws_size,
                              hipStream_t stream) {
  const float* inputs = (const float*)d_in[0];
  const int* segpos = (const int*)d_in[1];
  // d_in[2] = mask: causal tril, known analytically — unused.
  const float* w_in = (const float*)d_in[3];
  const float* w_out = (const float*)d_in[4];
  float* out = (float*)d_out;
  char* ws = (char*)d_ws;

  size_t o = 0;
  u16* Xbf = (u16*)(ws + o); o += (size_t)4096 * 1024 * 2;   // inputs bf16; reused as attn output
  u16* WinT = (u16*)(ws + o); o += (size_t)3072 * 1024 * 2;  // w_in^T bf16
  u16* WoutT = (u16*)(ws + o); o += (size_t)1024 * 1024 * 2; // w_out^T bf16
  u16* Qb = (u16*)(ws + o); o += (size_t)NBATCH * NH * SEQ * HD * 2;
  u16* Kb = (u16*)(ws + o); o += (size_t)NBATCH * NH * SEQ * HD * 2;  // raw K (gemm out)
  u16* Kf = (u16*)(ws + o); o += (size_t)NBATCH * NH * SEQ * HD * 2;  // fragment K (rope out)
  u16* Vt = (u16*)(ws + o); o += (size_t)NBATCH * NH * HD * SEQ * 2;  // fragment V
  float2* SC = (float2*)(ws + o); o += (size_t)SEQ * 32 * sizeof(float2);

  k_prep<<<8448, 256, 0, stream>>>(inputs, Xbf, w_in, WinT, w_out, WoutT, SC);
  k_gemm<0><<<dim3(24, 64), 256, 0, stream>>>(Xbf, WinT, 3072, Qb, Kb, Vt, nullptr);
  k_rope<<<512, 256, 0, stream>>>(Qb, Kb, Kf, segpos, SC);
  k_attn<<<1024, 256, 0, stream>>>(Qb, Kf, Vt, Xbf);
  k_gemm<1><<<dim3(8, 64), 256, 0, stream>>>(Xbf, WoutT, 1024, nullptr, nullptr, nullptr, out);
}